// Round 1
// baseline (316.798 us; speedup 1.0000x reference)
//
#include <hip/hip_runtime.h>
#include <hip/hip_fp16.h>

#define N_NODES_C 100000
#define N_EDGES_C 1200000
#define NBUK ((N_NODES_C + 255) >> 8)   // 391 buckets of 256 nodes
#define CHUNK 2048                       // edges per binning block
#define DCAP 4096                        // LDS cache for a bucket's staged edges
#define DBINS 64                         // degree-sort bins (clamp at 63)

typedef _Float16 f16x8 __attribute__((ext_vector_type(8)));
typedef float f32x4 __attribute__((ext_vector_type(4)));

// staged entry: col (bits 0..16) | bucket-relative row (bits 17..24)
#define PACK(r8, c) ((c) | ((r8) << 17))
#define UNPACK_C(v) ((v) & 0x1FFFF)
#define UNPACK_R(v) ((v) >> 17)

// ---------- merged: bucket histogram (blocks 0..histB-1) + fp32->fp16 convert ----------
__global__ __launch_bounds__(256) void hist_f2h(const int* __restrict__ ei,
                                                int* __restrict__ bucket_cnt,
                                                const float* __restrict__ x,
                                                __half* __restrict__ xh,
                                                int nedges, int n4, int histB) {
    __shared__ int cnt[NBUK];
    const int tid = threadIdx.x;
    if (blockIdx.x < histB) {
        const int base = blockIdx.x * CHUNK;
        const int nloc = min(CHUNK, nedges - base);
        for (int i = tid; i < NBUK; i += 256) cnt[i] = 0;
        __syncthreads();
        for (int i = tid; i < nloc; i += 256) atomicAdd(&cnt[ei[base + i] >> 8], 1);
        __syncthreads();
        for (int b = tid; b < NBUK; b += 256) {
            int n = cnt[b];
            if (n) atomicAdd(&bucket_cnt[b], n);
        }
    } else {
        int i = (blockIdx.x - histB) * 256 + tid;
        if (i < n4) {
            float4 v = ((const float4*)x)[i];
            __half2 tmp[2];
            tmp[0] = __floats2half2_rn(v.x, v.y);
            tmp[1] = __floats2half2_rn(v.z, v.w);
            ((float2*)xh)[i] = *(float2*)tmp;
        }
    }
}

// ---------- merged: block 0 scans bucket counts; blocks 1.. pack MFMA weights ----------
__global__ __launch_bounds__(256) void scan_fold(const int* __restrict__ bucket_cnt,
                                                 int* __restrict__ bucket_base,
                                                 int* __restrict__ bucket_next, int nb,
                                                 const float* __restrict__ W1,
                                                 const float* __restrict__ W2,
                                                 __half* __restrict__ W1f,
                                                 __half* __restrict__ W2f) {
    const int tid = threadIdx.x;
    if (blockIdx.x == 0) {
        __shared__ int s[256];
        int a0 = (2 * tid < nb) ? bucket_cnt[2 * tid] : 0;
        int a1 = (2 * tid + 1 < nb) ? bucket_cnt[2 * tid + 1] : 0;
        s[tid] = a0 + a1;
        __syncthreads();
        for (int off = 1; off < 256; off <<= 1) {
            int v = s[tid];
            int add = (tid >= off) ? s[tid - off] : 0;
            __syncthreads();
            s[tid] = v + add;
            __syncthreads();
        }
        int excl = (tid > 0) ? s[tid - 1] : 0;
        if (2 * tid < nb) { bucket_base[2 * tid] = excl; bucket_next[2 * tid] = excl; }
        if (2 * tid + 1 < nb) { bucket_base[2 * tid + 1] = excl + a0; bucket_next[2 * tid + 1] = excl + a0; }
        if (tid == 255) bucket_base[nb] = s[255];
        return;
    }
    int i = (blockIdx.x - 1) * 256 + tid;
    if (i < 12288) {                       // layer-1: [4 ct][6 kh][64 lane][8 j]
        int j = i & 7;
        int lane = (i >> 3) & 63;
        int rest = i >> 9;
        int kh = rest % 6;
        int ct = rest / 6;
        int term = kh >> 1;
        int k = ((kh & 1) << 5) | ((lane >> 4) << 3) | j;
        int c = (ct << 4) | (lane & 15);
        float w0 = W1[k * 64 + c];
        float w1 = W1[4096 + k * 64 + c];
        float w2 = W1[2 * 4096 + k * 64 + c];
        float v = (term == 0) ? (w0 - w2) : ((term == 1) ? w1 : 2.0f * w2);
        W1f[i] = __float2half(v);
    } else if (i < 12288 + 6144) {         // layer-2: [6 ct][2 kh][64 lane][8 j]
        int ii = i - 12288;
        int j = ii & 7;
        int lane = (ii >> 3) & 63;
        int rest = ii >> 9;
        int kh = rest & 1;
        int ct = rest >> 1;
        int k = (kh << 5) | ((lane >> 4) << 3) | j;
        int cg = ct * 16 + (lane & 15);
        int seg = cg >> 5;
        int c = cg & 31;
        float w0 = W2[k * 32 + c];
        float w1 = W2[2048 + k * 32 + c];
        float w2 = W2[2 * 2048 + k * 32 + c];
        float v = (seg == 0) ? (w0 - w2) : ((seg == 1) ? w1 : 2.0f * w2);
        W2f[ii] = __float2half(v);
    }
}

// ---------- phase B: LDS-binned staging grouped by 256-node bucket (packed int) ----------
__global__ __launch_bounds__(256) void bin_stage(const int* __restrict__ ei,
                                                 int* __restrict__ bucket_next,
                                                 int* __restrict__ staged, int nedges) {
    __shared__ int cnt[NBUK];
    __shared__ int ofs[NBUK];
    __shared__ int run[NBUK];
    __shared__ int gbase[NBUK];
    __shared__ int ssum[256];
    __shared__ int2 sedge[CHUNK];
    const int tid = threadIdx.x;
    const int base = blockIdx.x * CHUNK;
    const int nloc = min(CHUNK, nedges - base);

    for (int i = tid; i < NBUK; i += 256) { cnt[i] = 0; run[i] = 0; }
    __syncthreads();

    int r[8], c[8];
#pragma unroll
    for (int k = 0; k < 8; ++k) {
        int loc = tid + k * 256;
        bool ok = loc < nloc;
        int idx = base + loc;
        r[k] = ok ? ei[idx] : -1;
        c[k] = ok ? ei[nedges + idx] : 0;
        if (ok) atomicAdd(&cnt[r[k] >> 8], 1);
    }
    __syncthreads();

    int a0 = (2 * tid < NBUK) ? cnt[2 * tid] : 0;
    int a1 = (2 * tid + 1 < NBUK) ? cnt[2 * tid + 1] : 0;
    ssum[tid] = a0 + a1;
    __syncthreads();
    for (int off = 1; off < 256; off <<= 1) {
        int v = ssum[tid];
        int add = (tid >= off) ? ssum[tid - off] : 0;
        __syncthreads();
        ssum[tid] = v + add;
        __syncthreads();
    }
    int excl = (tid > 0) ? ssum[tid - 1] : 0;
    if (2 * tid < NBUK) ofs[2 * tid] = excl;
    if (2 * tid + 1 < NBUK) ofs[2 * tid + 1] = excl + a0;
    __syncthreads();

#pragma unroll
    for (int k = 0; k < 8; ++k) {
        if (r[k] >= 0) {
            int b = r[k] >> 8;
            int p = atomicAdd(&run[b], 1);
            sedge[ofs[b] + p] = make_int2(r[k], c[k]);
        }
    }
    __syncthreads();

    for (int b = tid; b < NBUK; b += 256) {
        int n = cnt[b];
        gbase[b] = n ? atomicAdd(&bucket_next[b], n) : 0;
    }
    __syncthreads();

    for (int i = tid; i < nloc; i += 256) {
        int2 e = sedge[i];
        int b = e.x >> 8;
        __builtin_nontemporal_store(PACK(e.x & 255, e.y), staged + gbase[b] + (i - ofs[b]));
    }
}

// ---------- phase C (merged): degree count -> rowptr + dis + exact CSR col placement ----------
__global__ __launch_bounds__(256) void bin_count_place(const int* __restrict__ staged,
                                                       const int* __restrict__ bucket_base,
                                                       int* __restrict__ rowptr,
                                                       float* __restrict__ dis,
                                                       int* __restrict__ colz,
                                                       int* __restrict__ deghist,
                                                       int nnodes, int nedges) {
    __shared__ int deg[256];
    __shared__ int ssum[256];
    __shared__ int rp[256];
    __shared__ int nx[256];
    __shared__ int dh[DBINS];
    __shared__ int cache[DCAP];
    const int b = blockIdx.x;
    const int n0 = b << 8;
    const int nend = min(n0 + 256, nnodes);
    const int nloc = nend - n0;
    const int tid = threadIdx.x;
    deg[tid] = 0;
    nx[tid] = 0;
    if (tid < DBINS) dh[tid] = 0;
    __syncthreads();
    const int ebase = bucket_base[b];
    const int ecount = bucket_base[b + 1] - ebase;
    for (int i = tid; i < ecount; i += 256) {
        int v = __builtin_nontemporal_load(staged + ebase + i);
        if (i < DCAP) cache[i] = v;
        atomicAdd(&deg[UNPACK_R(v)], 1);
    }
    __syncthreads();
    int d = deg[tid];
    if (tid < nloc) {
        float df = (float)d;
        dis[n0 + tid] = (d > 0) ? (1.0f / sqrtf(fmaxf(df, 1.f))) : 0.f;
        atomicAdd(&dh[min(d, DBINS - 1)], 1);
    }
    ssum[tid] = d;
    __syncthreads();
    for (int off = 1; off < 256; off <<= 1) {
        int v = ssum[tid];
        int add = (tid >= off) ? ssum[tid - off] : 0;
        __syncthreads();
        ssum[tid] = v + add;
        __syncthreads();
    }
    int excl = (tid > 0) ? ssum[tid - 1] : 0;
    rp[tid] = ebase + excl;
    if (tid < nloc) rowptr[n0 + tid] = ebase + excl;
    if (b == NBUK - 1 && tid == 0) rowptr[nnodes] = nedges;
    if (tid < DBINS) {
        int cn = dh[tid];
        if (cn) atomicAdd(&deghist[tid], cn);
    }
    __syncthreads();
    for (int i = tid; i < ecount; i += 256) {
        int v = (i < DCAP) ? cache[i] : staged[ebase + i];
        int rrel = UNPACK_R(v);
        int col = UNPACK_C(v);
        int p = atomicAdd(&nx[rrel], 1);
        __builtin_nontemporal_store(col, colz + rp[rrel] + p);
    }
}

// ---------- degree counting-sort scatter: perm groups equal-degree nodes ----------
__global__ __launch_bounds__(256) void deg_scatter(const int* __restrict__ rowptr,
                                                   const int* __restrict__ deghist,
                                                   int* __restrict__ dnext,
                                                   int* __restrict__ perm, int nnodes) {
    __shared__ int gbase[DBINS];
    __shared__ int lcnt[DBINS];
    __shared__ int lbase[DBINS];
    const int tid = threadIdx.x;
    if (tid == 0) {
        int runv = 0;
        for (int i = 0; i < DBINS; ++i) { gbase[i] = runv; runv += deghist[i]; }
    }
    if (tid < DBINS) lcnt[tid] = 0;
    __syncthreads();
    int n = blockIdx.x * 256 + tid;
    int bn = 0, lp = 0;
    bool ok = n < nnodes;
    if (ok) {
        int d = rowptr[n + 1] - rowptr[n];
        bn = min(d, DBINS - 1);
        lp = atomicAdd(&lcnt[bn], 1);
    }
    __syncthreads();
    if (tid < DBINS) {
        int cn = lcnt[tid];
        lbase[tid] = cn ? atomicAdd(&dnext[tid], cn) : 0;
    }
    __syncthreads();
    if (ok) perm[gbase[bn] + lbase[bn] + lp] = n;
}

// ---------- prop64: 8-lane groups, 8 nodes/wave, degree-sorted walks, on-the-fly w ----------
__global__ __launch_bounds__(256) void prop_gather_h(const __half* __restrict__ t,
                                                     const int* __restrict__ rowptr,
                                                     const int* __restrict__ colz,
                                                     const float* __restrict__ dis,
                                                     const int* __restrict__ perm,
                                                     __half* __restrict__ out, int nnodes) {
    int grp = threadIdx.x >> 3;          // 0..31 within block
    int ln = threadIdx.x & 7;            // 16B chunk: ch 8*ln .. 8*ln+7
    int idx = blockIdx.x * 32 + grp;
    if (idx >= nnodes) return;
    int node = perm[idx];
    int s = rowptr[node];
    int e = rowptr[node + 1];
    float nds = -dis[node];
    float acc[8] = {0.f, 0.f, 0.f, 0.f, 0.f, 0.f, 0.f, 0.f};
    int i = s;
    for (; i + 3 < e; i += 4) {
        int c0 = __builtin_nontemporal_load(colz + i);
        int c1 = __builtin_nontemporal_load(colz + i + 1);
        int c2 = __builtin_nontemporal_load(colz + i + 2);
        int c3 = __builtin_nontemporal_load(colz + i + 3);
        float4 r0 = ((const float4*)(t + (size_t)c0 * 64))[ln];
        float4 r1 = ((const float4*)(t + (size_t)c1 * 64))[ln];
        float4 r2 = ((const float4*)(t + (size_t)c2 * 64))[ln];
        float4 r3 = ((const float4*)(t + (size_t)c3 * 64))[ln];
        float w0 = nds * dis[c0];
        float w1 = nds * dis[c1];
        float w2 = nds * dis[c2];
        float w3 = nds * dis[c3];
        const __half2* h0 = (const __half2*)&r0;
        const __half2* h1 = (const __half2*)&r1;
        const __half2* h2 = (const __half2*)&r2;
        const __half2* h3 = (const __half2*)&r3;
#pragma unroll
        for (int q = 0; q < 4; ++q) {
            float2 f0 = __half22float2(h0[q]);
            float2 f1 = __half22float2(h1[q]);
            float2 f2 = __half22float2(h2[q]);
            float2 f3 = __half22float2(h3[q]);
            acc[2 * q + 0] += w0 * f0.x + w1 * f1.x + w2 * f2.x + w3 * f3.x;
            acc[2 * q + 1] += w0 * f0.y + w1 * f1.y + w2 * f2.y + w3 * f3.y;
        }
    }
    for (; i < e; ++i) {
        int c0 = __builtin_nontemporal_load(colz + i);
        float w0 = nds * dis[c0];
        float4 r0 = ((const float4*)(t + (size_t)c0 * 64))[ln];
        const __half2* h0 = (const __half2*)&r0;
#pragma unroll
        for (int q = 0; q < 4; ++q) {
            float2 f0 = __half22float2(h0[q]);
            acc[2 * q + 0] += w0 * f0.x;
            acc[2 * q + 1] += w0 * f0.y;
        }
    }
    __half2 tmp[4];
    tmp[0] = __floats2half2_rn(acc[0], acc[1]);
    tmp[1] = __floats2half2_rn(acc[2], acc[3]);
    tmp[2] = __floats2half2_rn(acc[4], acc[5]);
    tmp[3] = __floats2half2_rn(acc[6], acc[7]);
    ((float4*)(out + (size_t)node * 64))[ln] = *(float4*)tmp;
}

// ---------- prop32: 4-lane groups, 16 nodes/wave, degree-sorted walks, on-the-fly w ----------
template <bool F32OUT>
__global__ __launch_bounds__(256) void prop_gather32(const __half* __restrict__ t,
                                                     const int* __restrict__ rowptr,
                                                     const int* __restrict__ colz,
                                                     const float* __restrict__ dis,
                                                     const int* __restrict__ perm,
                                                     const void* __restrict__ addin,
                                                     void* __restrict__ outv, int nnodes) {
    int grp = threadIdx.x >> 2;          // 0..63 within block
    int ln = threadIdx.x & 3;            // 16B chunk: ch 8*ln .. 8*ln+7
    int idx = blockIdx.x * 64 + grp;
    if (idx >= nnodes) return;
    int node = perm[idx];
    int s = rowptr[node];
    int e = rowptr[node + 1];
    float nds = -dis[node];
    float acc[8] = {0.f, 0.f, 0.f, 0.f, 0.f, 0.f, 0.f, 0.f};
    int i = s;
    for (; i + 3 < e; i += 4) {
        int c0 = __builtin_nontemporal_load(colz + i);
        int c1 = __builtin_nontemporal_load(colz + i + 1);
        int c2 = __builtin_nontemporal_load(colz + i + 2);
        int c3 = __builtin_nontemporal_load(colz + i + 3);
        float4 r0 = ((const float4*)(t + (size_t)c0 * 32))[ln];
        float4 r1 = ((const float4*)(t + (size_t)c1 * 32))[ln];
        float4 r2 = ((const float4*)(t + (size_t)c2 * 32))[ln];
        float4 r3 = ((const float4*)(t + (size_t)c3 * 32))[ln];
        float w0 = nds * dis[c0];
        float w1 = nds * dis[c1];
        float w2 = nds * dis[c2];
        float w3 = nds * dis[c3];
        const __half2* h0 = (const __half2*)&r0;
        const __half2* h1 = (const __half2*)&r1;
        const __half2* h2 = (const __half2*)&r2;
        const __half2* h3 = (const __half2*)&r3;
#pragma unroll
        for (int q = 0; q < 4; ++q) {
            float2 f0 = __half22float2(h0[q]);
            float2 f1 = __half22float2(h1[q]);
            float2 f2 = __half22float2(h2[q]);
            float2 f3 = __half22float2(h3[q]);
            acc[2 * q + 0] += w0 * f0.x + w1 * f1.x + w2 * f2.x + w3 * f3.x;
            acc[2 * q + 1] += w0 * f0.y + w1 * f1.y + w2 * f2.y + w3 * f3.y;
        }
    }
    for (; i < e; ++i) {
        int c0 = __builtin_nontemporal_load(colz + i);
        float w0 = nds * dis[c0];
        float4 r0 = ((const float4*)(t + (size_t)c0 * 32))[ln];
        const __half2* h0 = (const __half2*)&r0;
#pragma unroll
        for (int q = 0; q < 4; ++q) {
            float2 f0 = __half22float2(h0[q]);
            acc[2 * q + 0] += w0 * f0.x;
            acc[2 * q + 1] += w0 * f0.y;
        }
    }
    if (F32OUT) {
        const float* add = (const float*)addin;
        float* out = (float*)outv;
        float4 a0 = ((const float4*)(add + (size_t)node * 32))[ln * 2 + 0];
        float4 a1 = ((const float4*)(add + (size_t)node * 32))[ln * 2 + 1];
        a0.x += acc[0]; a0.y += acc[1]; a0.z += acc[2]; a0.w += acc[3];
        a1.x += acc[4]; a1.y += acc[5]; a1.z += acc[6]; a1.w += acc[7];
        ((float4*)(out + (size_t)node * 32))[ln * 2 + 0] = a0;
        ((float4*)(out + (size_t)node * 32))[ln * 2 + 1] = a1;
    } else {
        const __half* add = (const __half*)addin;
        __half* out = (__half*)outv;
        float4 raw = ((const float4*)(add + (size_t)node * 32))[ln];
        const __half2* hp = (const __half2*)&raw;
        float2 a0 = __half22float2(hp[0]);
        float2 a1 = __half22float2(hp[1]);
        float2 a2 = __half22float2(hp[2]);
        float2 a3 = __half22float2(hp[3]);
        __half2 tmp[4];
        tmp[0] = __floats2half2_rn(acc[0] + a0.x, acc[1] + a0.y);
        tmp[1] = __floats2half2_rn(acc[2] + a1.x, acc[3] + a1.y);
        tmp[2] = __floats2half2_rn(acc[4] + a2.x, acc[5] + a2.y);
        tmp[3] = __floats2half2_rn(acc[6] + a3.x, acc[7] + a3.y);
        ((float4*)(out + (size_t)node * 32))[ln] = *(float4*)tmp;
    }
}

// ---------- FUSED both-layer MFMA GEMM ----------
__global__ __launch_bounds__(256) void gemm_fused(const __half* __restrict__ A0,
                                                  const __half* __restrict__ A1,
                                                  const __half* __restrict__ A2,
                                                  const __half* __restrict__ W1f,
                                                  const float* __restrict__ b1,
                                                  const __half* __restrict__ W2f,
                                                  const float* __restrict__ b2,
                                                  float* __restrict__ P0,
                                                  __half* __restrict__ G1,
                                                  __half* __restrict__ G2, int nnodes) {
    __shared__ __align__(16) __half htile[4][16 * 72];   // 9 KB
    const int wave = threadIdx.x >> 6;
    const int lane = threadIdx.x & 63;
    const int node0 = blockIdx.x * 64 + wave * 16;
    const int m = lane & 15;
    const int quad = lane >> 4;
    int arow = node0 + m;
    if (arow >= nnodes) arow = nnodes - 1;   // clamp: garbage rows never stored globally

    // ---- layer 1 ----
    const __half* Ap[3] = {A0, A1, A2};
    f16x8 a[6];
#pragma unroll
    for (int kh = 0; kh < 6; ++kh) {
        const __half* A = Ap[kh >> 1];
        a[kh] = *(const f16x8*)(A + (size_t)arow * 64 + ((kh & 1) << 5) + (quad << 3));
    }
    __half* ht = htile[wave];
#pragma unroll
    for (int ct = 0; ct < 4; ++ct) {
        f32x4 acc = {0.f, 0.f, 0.f, 0.f};
#pragma unroll
        for (int kh = 0; kh < 6; ++kh) {
            f16x8 b = *(const f16x8*)(W1f + ((size_t)(ct * 6 + kh) * 64 + lane) * 8);
            acc = __builtin_amdgcn_mfma_f32_16x16x32_f16(a[kh], b, acc, 0, 0, 0);
        }
        int col = (ct << 4) | m;
        float bias = b1[col];
#pragma unroll
        for (int r = 0; r < 4; ++r) {
            ht[(quad * 4 + r) * 72 + col] = __float2half(fmaxf(acc[r] + bias, 0.f));
        }
    }
    __syncthreads();

    // ---- layer 2: A-frags straight from the LDS tile ----
    f16x8 h0 = *(const f16x8*)(ht + m * 72 + (quad << 3));
    f16x8 h1 = *(const f16x8*)(ht + m * 72 + 32 + (quad << 3));
#pragma unroll
    for (int ct = 0; ct < 6; ++ct) {
        f32x4 acc = {0.f, 0.f, 0.f, 0.f};
        f16x8 b0 = *(const f16x8*)(W2f + ((size_t)(ct * 2 + 0) * 64 + lane) * 8);
        f16x8 b1v = *(const f16x8*)(W2f + ((size_t)(ct * 2 + 1) * 64 + lane) * 8);
        acc = __builtin_amdgcn_mfma_f32_16x16x32_f16(h0, b0, acc, 0, 0, 0);
        acc = __builtin_amdgcn_mfma_f32_16x16x32_f16(h1, b1v, acc, 0, 0, 0);
        int seg = ct >> 1;                      // wave-uniform
        int c = ((ct & 1) << 4) | m;            // col within segment
#pragma unroll
        for (int r = 0; r < 4; ++r) {
            int n = node0 + (quad << 2) + r;
            if (n >= nnodes) continue;
            float v = acc[r];
            if (seg == 0)      P0[(size_t)n * 32 + c] = v + b2[c];
            else if (seg == 1) G1[(size_t)n * 32 + c] = __float2half(v);
            else               G2[(size_t)n * 32 + c] = __float2half(v);
        }
    }
}

extern "C" void kernel_launch(void* const* d_in, const int* in_sizes, int n_in,
                              void* d_out, int out_size, void* d_ws, size_t ws_size,
                              hipStream_t stream) {
    const float* x  = (const float*)d_in[0];
    const int*   ei = (const int*)d_in[1];
    const float* W1 = (const float*)d_in[2];
    const float* b1 = (const float*)d_in[3];
    const float* W2 = (const float*)d_in[4];
    const float* b2 = (const float*)d_in[5];
    float* out = (float*)d_out;

    const int NN = N_NODES_C;
    const int NE = N_EDGES_C;
    const size_t HFEAT_BYTES = (size_t)NN * 64 * sizeof(__half);
    const size_t H32_BYTES = (size_t)NN * 32 * sizeof(__half);

    char* ws = (char*)d_ws;
    size_t off = 0;
    auto alloc = [&](size_t bytes) -> void* {
        void* p = ws + off;
        off += (bytes + 255) & ~(size_t)255;
        return p;
    };
    int*    bucket_cnt  = (int*)alloc((size_t)NBUK * 4);
    int*    deghist     = (int*)alloc((size_t)DBINS * 4);
    int*    dnext       = (int*)alloc((size_t)DBINS * 4);
    int*    bucket_base = (int*)alloc((size_t)(NBUK + 1) * 4);
    int*    bucket_next = (int*)alloc((size_t)NBUK * 4);
    int*    rowptr      = (int*)alloc((size_t)(NN + 1) * 4);
    float*  dis         = (float*)alloc((size_t)NN * 4);
    int*    perm        = (int*)alloc((size_t)NN * 4);
    int*    staged      = (int*)alloc((size_t)NE * 4);
    int*    colz        = (int*)alloc((size_t)NE * 4);
    __half* xh          = (__half*)alloc(HFEAT_BYTES);
    __half* T1h         = (__half*)alloc(HFEAT_BYTES);   // layer1: T1; layer2: G1
    __half* T2h         = (__half*)alloc(HFEAT_BYTES);   // layer1: T2; layer2: G2
    __half* Qh          = (__half*)alloc(H32_BYTES);
    float*  P0          = (float*)alloc((size_t)NN * 32 * 4);
    __half* W1f         = (__half*)alloc((size_t)4 * 6 * 64 * 8 * 2);   // 24 KB
    __half* W2f         = (__half*)alloc((size_t)6 * 2 * 64 * 8 * 2);   // 12 KB

    const int PROPB = (NN + 31) / 32;     // prop64: 32 nodes/block
    const int PROP32B = (NN + 63) / 64;   // prop32: 64 nodes/block
    const int CONV4 = NN * 64 / 4;
    const int CONVB = (CONV4 + 255) / 256;
    const int BINB = (NE + CHUNK - 1) / CHUNK;
    const int GEMMB = (NN + 63) / 64;
    const int FOLDB = 1 + (18432 + 255) / 256;
    const int SCATB = (NN + 255) / 256;

    // ---- CSR build (bucket-atomic) + weight packing + x->fp16 ----
    size_t zbytes = (size_t)((char*)dnext - (char*)bucket_cnt) + 256;   // cnt+deghist+dnext
    hipMemsetAsync(bucket_cnt, 0, zbytes, stream);
    hist_f2h<<<BINB + CONVB, 256, 0, stream>>>(ei, bucket_cnt, x, xh, NE, CONV4, BINB);
    scan_fold<<<FOLDB, 256, 0, stream>>>(bucket_cnt, bucket_base, bucket_next, NBUK,
                                         W1, W2, W1f, W2f);
    bin_stage<<<BINB, 256, 0, stream>>>(ei, bucket_next, staged, NE);
    bin_count_place<<<NBUK, 256, 0, stream>>>(staged, bucket_base, rowptr, dis, colz,
                                              deghist, NN, NE);
    deg_scatter<<<SCATB, 256, 0, stream>>>(rowptr, deghist, dnext, perm, NN);

    // ---- layer 1 props, then fused both-layer GEMM ----
    prop_gather_h<<<PROPB, 256, 0, stream>>>(xh, rowptr, colz, dis, perm, T1h, NN);
    prop_gather_h<<<PROPB, 256, 0, stream>>>(T1h, rowptr, colz, dis, perm, T2h, NN);
    gemm_fused<<<GEMMB, 256, 0, stream>>>(xh, T1h, T2h, W1f, b1, W2f, b2, P0, T1h, T2h, NN);

    // ---- layer 2 (factored): out = P0 + prop(G1 + prop(G2)) ----
    prop_gather32<false><<<PROP32B, 256, 0, stream>>>(T2h, rowptr, colz, dis, perm, T1h, Qh, NN);
    prop_gather32<true><<<PROP32B, 256, 0, stream>>>(Qh, rowptr, colz, dis, perm, P0, out, NN);
}

// Round 2
// 255.225 us; speedup vs baseline: 1.2413x; 1.2413x over previous
//
#include <hip/hip_runtime.h>
#include <hip/hip_fp16.h>

#define N_NODES_C 100000
#define N_EDGES_C 1200000
#define NBUK ((N_NODES_C + 255) >> 8)   // 391 buckets of 256 nodes
#define CHUNK 4096                       // edges per binning block

typedef _Float16 f16x8 __attribute__((ext_vector_type(8)));
typedef float f32x4 __attribute__((ext_vector_type(4)));

// staged entry: col (bits 0..16) | bucket-relative row (bits 17..24)
#define PACK(r8, c) ((c) | ((r8) << 17))
#define UNPACK_C(v) ((v) & 0x1FFFF)
#define UNPACK_R(v) ((v) >> 17)

// ---------- merged: bucket histogram (blocks 0..histB-1) + fp32->fp16 convert ----------
__global__ __launch_bounds__(256) void hist_f2h(const int* __restrict__ ei,
                                                int* __restrict__ bucket_cnt,
                                                const float* __restrict__ x,
                                                __half* __restrict__ xh,
                                                int nedges, int n4, int histB) {
    __shared__ int cnt[NBUK];
    const int tid = threadIdx.x;
    if (blockIdx.x < histB) {
        const int base = blockIdx.x * CHUNK;
        const int nloc = min(CHUNK, nedges - base);
        for (int i = tid; i < NBUK; i += 256) cnt[i] = 0;
        __syncthreads();
        for (int i = tid; i < nloc; i += 256) atomicAdd(&cnt[ei[base + i] >> 8], 1);
        __syncthreads();
        for (int b = tid; b < NBUK; b += 256) {
            int n = cnt[b];
            if (n) atomicAdd(&bucket_cnt[b], n);
        }
    } else {
        int i = (blockIdx.x - histB) * 256 + tid;
        if (i < n4) {
            float4 v = ((const float4*)x)[i];
            __half2 tmp[2];
            tmp[0] = __floats2half2_rn(v.x, v.y);
            tmp[1] = __floats2half2_rn(v.z, v.w);
            ((float2*)xh)[i] = *(float2*)tmp;
        }
    }
}

// ---------- merged: block 0 scans bucket counts; blocks 1.. pack MFMA weights ----------
__global__ __launch_bounds__(256) void scan_fold(const int* __restrict__ bucket_cnt,
                                                 int* __restrict__ bucket_base,
                                                 int* __restrict__ bucket_next, int nb,
                                                 const float* __restrict__ W1,
                                                 const float* __restrict__ W2,
                                                 __half* __restrict__ W1f,
                                                 __half* __restrict__ W2f) {
    const int tid = threadIdx.x;
    if (blockIdx.x == 0) {
        __shared__ int s[256];
        int a0 = (2 * tid < nb) ? bucket_cnt[2 * tid] : 0;
        int a1 = (2 * tid + 1 < nb) ? bucket_cnt[2 * tid + 1] : 0;
        s[tid] = a0 + a1;
        __syncthreads();
        for (int off = 1; off < 256; off <<= 1) {
            int v = s[tid];
            int add = (tid >= off) ? s[tid - off] : 0;
            __syncthreads();
            s[tid] = v + add;
            __syncthreads();
        }
        int excl = (tid > 0) ? s[tid - 1] : 0;
        if (2 * tid < nb) { bucket_base[2 * tid] = excl; bucket_next[2 * tid] = excl; }
        if (2 * tid + 1 < nb) { bucket_base[2 * tid + 1] = excl + a0; bucket_next[2 * tid + 1] = excl + a0; }
        if (tid == 255) bucket_base[nb] = s[255];
        return;
    }
    int i = (blockIdx.x - 1) * 256 + tid;
    if (i < 12288) {                       // layer-1: [4 ct][6 kh][64 lane][8 j]
        int j = i & 7;
        int lane = (i >> 3) & 63;
        int rest = i >> 9;
        int kh = rest % 6;
        int ct = rest / 6;
        int term = kh >> 1;
        int k = ((kh & 1) << 5) | ((lane >> 4) << 3) | j;
        int c = (ct << 4) | (lane & 15);
        float w0 = W1[k * 64 + c];
        float w1 = W1[4096 + k * 64 + c];
        float w2 = W1[2 * 4096 + k * 64 + c];
        float v = (term == 0) ? (w0 - w2) : ((term == 1) ? w1 : 2.0f * w2);
        W1f[i] = __float2half(v);
    } else if (i < 12288 + 6144) {         // layer-2: [6 ct][2 kh][64 lane][8 j]
        int ii = i - 12288;
        int j = ii & 7;
        int lane = (ii >> 3) & 63;
        int rest = ii >> 9;
        int kh = rest & 1;
        int ct = rest >> 1;
        int k = (kh << 5) | ((lane >> 4) << 3) | j;
        int cg = ct * 16 + (lane & 15);
        int seg = cg >> 5;
        int c = cg & 31;
        float w0 = W2[k * 32 + c];
        float w1 = W2[2048 + k * 32 + c];
        float w2 = W2[2 * 2048 + k * 32 + c];
        float v = (seg == 0) ? (w0 - w2) : ((seg == 1) ? w1 : 2.0f * w2);
        W2f[ii] = __float2half(v);
    }
}

// ---------- phase B: LDS-binned staging grouped by 256-node bucket (packed int) ----------
__global__ __launch_bounds__(256) void bin_stage(const int* __restrict__ ei,
                                                 int* __restrict__ bucket_next,
                                                 int* __restrict__ staged, int nedges) {
    __shared__ int cnt[NBUK];
    __shared__ int ofs[NBUK];
    __shared__ int run[NBUK];
    __shared__ int gbase[NBUK];
    __shared__ int ssum[256];
    __shared__ int2 sedge[CHUNK];
    const int tid = threadIdx.x;
    const int base = blockIdx.x * CHUNK;
    const int nloc = min(CHUNK, nedges - base);

    for (int i = tid; i < NBUK; i += 256) { cnt[i] = 0; run[i] = 0; }
    __syncthreads();

    int r[16], c[16];
#pragma unroll
    for (int k = 0; k < 16; ++k) {
        int loc = tid + k * 256;
        bool ok = loc < nloc;
        int idx = base + loc;
        r[k] = ok ? ei[idx] : -1;
        c[k] = ok ? ei[nedges + idx] : 0;
        if (ok) atomicAdd(&cnt[r[k] >> 8], 1);
    }
    __syncthreads();

    int a0 = (2 * tid < NBUK) ? cnt[2 * tid] : 0;
    int a1 = (2 * tid + 1 < NBUK) ? cnt[2 * tid + 1] : 0;
    ssum[tid] = a0 + a1;
    __syncthreads();
    for (int off = 1; off < 256; off <<= 1) {
        int v = ssum[tid];
        int add = (tid >= off) ? ssum[tid - off] : 0;
        __syncthreads();
        ssum[tid] = v + add;
        __syncthreads();
    }
    int excl = (tid > 0) ? ssum[tid - 1] : 0;
    if (2 * tid < NBUK) ofs[2 * tid] = excl;
    if (2 * tid + 1 < NBUK) ofs[2 * tid + 1] = excl + a0;
    __syncthreads();

#pragma unroll
    for (int k = 0; k < 16; ++k) {
        if (r[k] >= 0) {
            int b = r[k] >> 8;
            int p = atomicAdd(&run[b], 1);
            sedge[ofs[b] + p] = make_int2(r[k], c[k]);
        }
    }
    __syncthreads();

    for (int b = tid; b < NBUK; b += 256) {
        int n = cnt[b];
        gbase[b] = n ? atomicAdd(&bucket_next[b], n) : 0;
    }
    __syncthreads();

    for (int i = tid; i < nloc; i += 256) {
        int2 e = sedge[i];
        int b = e.x >> 8;
        staged[gbase[b] + (i - ofs[b])] = PACK(e.x & 255, e.y);
    }
}

// ---------- phase C1: per-bucket degree count -> rowptr slice + deg_inv_sqrt ----------
__global__ __launch_bounds__(256) void bin_count(const int* __restrict__ staged,
                                                 const int* __restrict__ bucket_base,
                                                 int* __restrict__ rowptr, float* __restrict__ dis,
                                                 int nnodes, int nedges) {
    __shared__ int deg[256];
    __shared__ int ssum[256];
    const int b = blockIdx.x;
    const int n0 = b << 8;
    const int nend = min(n0 + 256, nnodes);
    const int nloc = nend - n0;
    const int tid = threadIdx.x;
    deg[tid] = 0;
    __syncthreads();
    const int ebase = bucket_base[b];
    const int ecount = bucket_base[b + 1] - ebase;
    for (int i = tid; i < ecount; i += 256) {
        atomicAdd(&deg[UNPACK_R(staged[ebase + i])], 1);
    }
    __syncthreads();
    int d = deg[tid];
    if (tid < nloc) {
        float df = (float)d;
        dis[n0 + tid] = (d > 0) ? (1.0f / sqrtf(fmaxf(df, 1.f))) : 0.f;
    }
    ssum[tid] = d;
    __syncthreads();
    for (int off = 1; off < 256; off <<= 1) {
        int v = ssum[tid];
        int add = (tid >= off) ? ssum[tid - off] : 0;
        __syncthreads();
        ssum[tid] = v + add;
        __syncthreads();
    }
    int excl = (tid > 0) ? ssum[tid - 1] : 0;
    if (tid < nloc) rowptr[n0 + tid] = ebase + excl;
    if (b == NBUK - 1 && tid == 0) rowptr[nnodes] = nedges;
}

// ---------- phase C2: per-bucket exact CSR placement + norm weight ----------
__global__ __launch_bounds__(256) void bin_place(const int* __restrict__ staged,
                                                 const int* __restrict__ rowptr,
                                                 const float* __restrict__ dis,
                                                 int2* __restrict__ colw, int nnodes) {
    __shared__ int rp[256];
    __shared__ int nx[256];
    __shared__ float dl[256];
    const int b = blockIdx.x;
    const int n0 = b << 8;
    const int nend = min(n0 + 256, nnodes);
    const int nloc = nend - n0;
    const int tid = threadIdx.x;
    if (tid < nloc) {
        rp[tid] = rowptr[n0 + tid];
        dl[tid] = dis[n0 + tid];
    }
    nx[tid] = 0;
    __syncthreads();
    const int ebase = rowptr[n0];
    const int ecount = rowptr[nend] - ebase;
    for (int i = tid; i < ecount; i += 256) {
        int v = staged[ebase + i];
        int col = UNPACK_C(v);
        int rrel = UNPACK_R(v);
        int p = atomicAdd(&nx[rrel], 1);
        float w = -dl[rrel] * dis[col];
        colw[rp[rrel] + p] = make_int2(col, __float_as_int(w));
    }
}

// ---------- prop64: 8-lane groups, 8 nodes/wave, 8-deep gather batches ----------
__global__ __launch_bounds__(256) void prop_gather_h(const __half* __restrict__ t,
                                                     const int* __restrict__ rowptr,
                                                     const int2* __restrict__ colw,
                                                     __half* __restrict__ out, int nnodes) {
    int grp = threadIdx.x >> 3;          // 0..31 within block
    int ln = threadIdx.x & 7;            // 16B chunk: ch 8*ln .. 8*ln+7
    int node = blockIdx.x * 32 + grp;
    if (node >= nnodes) return;
    int s = rowptr[node];
    int e = rowptr[node + 1];
    float acc[8] = {0.f, 0.f, 0.f, 0.f, 0.f, 0.f, 0.f, 0.f};
    int i = s;
    for (; i + 7 < e; i += 8) {
        int2 cw[8];
#pragma unroll
        for (int k = 0; k < 8; ++k) cw[k] = colw[i + k];
        float4 r[8];
#pragma unroll
        for (int k = 0; k < 8; ++k) r[k] = ((const float4*)(t + (size_t)cw[k].x * 64))[ln];
#pragma unroll
        for (int k = 0; k < 8; ++k) {
            float w = __int_as_float(cw[k].y);
            const __half2* h = (const __half2*)&r[k];
#pragma unroll
            for (int q = 0; q < 4; ++q) {
                float2 f = __half22float2(h[q]);
                acc[2 * q + 0] += w * f.x;
                acc[2 * q + 1] += w * f.y;
            }
        }
    }
    for (; i + 3 < e; i += 4) {
        int2 cw[4];
#pragma unroll
        for (int k = 0; k < 4; ++k) cw[k] = colw[i + k];
        float4 r[4];
#pragma unroll
        for (int k = 0; k < 4; ++k) r[k] = ((const float4*)(t + (size_t)cw[k].x * 64))[ln];
#pragma unroll
        for (int k = 0; k < 4; ++k) {
            float w = __int_as_float(cw[k].y);
            const __half2* h = (const __half2*)&r[k];
#pragma unroll
            for (int q = 0; q < 4; ++q) {
                float2 f = __half22float2(h[q]);
                acc[2 * q + 0] += w * f.x;
                acc[2 * q + 1] += w * f.y;
            }
        }
    }
    for (; i < e; ++i) {
        int2 cw0 = colw[i];
        float w0 = __int_as_float(cw0.y);
        float4 r0 = ((const float4*)(t + (size_t)cw0.x * 64))[ln];
        const __half2* h0 = (const __half2*)&r0;
#pragma unroll
        for (int q = 0; q < 4; ++q) {
            float2 f0 = __half22float2(h0[q]);
            acc[2 * q + 0] += w0 * f0.x;
            acc[2 * q + 1] += w0 * f0.y;
        }
    }
    __half2 tmp[4];
    tmp[0] = __floats2half2_rn(acc[0], acc[1]);
    tmp[1] = __floats2half2_rn(acc[2], acc[3]);
    tmp[2] = __floats2half2_rn(acc[4], acc[5]);
    tmp[3] = __floats2half2_rn(acc[6], acc[7]);
    ((float4*)(out + (size_t)node * 64))[ln] = *(float4*)tmp;
}

// ---------- prop32: 4-lane groups, 16 nodes/wave, 8-deep gather batches ----------
template <bool F32OUT>
__global__ __launch_bounds__(256) void prop_gather32(const __half* __restrict__ t,
                                                     const int* __restrict__ rowptr,
                                                     const int2* __restrict__ colw,
                                                     const void* __restrict__ addin,
                                                     void* __restrict__ outv, int nnodes) {
    int grp = threadIdx.x >> 2;          // 0..63 within block
    int ln = threadIdx.x & 3;            // 16B chunk: ch 8*ln .. 8*ln+7
    int node = blockIdx.x * 64 + grp;
    if (node >= nnodes) return;
    int s = rowptr[node];
    int e = rowptr[node + 1];
    float acc[8] = {0.f, 0.f, 0.f, 0.f, 0.f, 0.f, 0.f, 0.f};
    int i = s;
    for (; i + 7 < e; i += 8) {
        int2 cw[8];
#pragma unroll
        for (int k = 0; k < 8; ++k) cw[k] = colw[i + k];
        float4 r[8];
#pragma unroll
        for (int k = 0; k < 8; ++k) r[k] = ((const float4*)(t + (size_t)cw[k].x * 32))[ln];
#pragma unroll
        for (int k = 0; k < 8; ++k) {
            float w = __int_as_float(cw[k].y);
            const __half2* h = (const __half2*)&r[k];
#pragma unroll
            for (int q = 0; q < 4; ++q) {
                float2 f = __half22float2(h[q]);
                acc[2 * q + 0] += w * f.x;
                acc[2 * q + 1] += w * f.y;
            }
        }
    }
    for (; i + 3 < e; i += 4) {
        int2 cw[4];
#pragma unroll
        for (int k = 0; k < 4; ++k) cw[k] = colw[i + k];
        float4 r[4];
#pragma unroll
        for (int k = 0; k < 4; ++k) r[k] = ((const float4*)(t + (size_t)cw[k].x * 32))[ln];
#pragma unroll
        for (int k = 0; k < 4; ++k) {
            float w = __int_as_float(cw[k].y);
            const __half2* h = (const __half2*)&r[k];
#pragma unroll
            for (int q = 0; q < 4; ++q) {
                float2 f = __half22float2(h[q]);
                acc[2 * q + 0] += w * f.x;
                acc[2 * q + 1] += w * f.y;
            }
        }
    }
    for (; i < e; ++i) {
        int2 cw0 = colw[i];
        float w0 = __int_as_float(cw0.y);
        float4 r0 = ((const float4*)(t + (size_t)cw0.x * 32))[ln];
        const __half2* h0 = (const __half2*)&r0;
#pragma unroll
        for (int q = 0; q < 4; ++q) {
            float2 f0 = __half22float2(h0[q]);
            acc[2 * q + 0] += w0 * f0.x;
            acc[2 * q + 1] += w0 * f0.y;
        }
    }
    if (F32OUT) {
        const float* add = (const float*)addin;
        float* out = (float*)outv;
        float4 a0 = ((const float4*)(add + (size_t)node * 32))[ln * 2 + 0];
        float4 a1 = ((const float4*)(add + (size_t)node * 32))[ln * 2 + 1];
        a0.x += acc[0]; a0.y += acc[1]; a0.z += acc[2]; a0.w += acc[3];
        a1.x += acc[4]; a1.y += acc[5]; a1.z += acc[6]; a1.w += acc[7];
        ((float4*)(out + (size_t)node * 32))[ln * 2 + 0] = a0;
        ((float4*)(out + (size_t)node * 32))[ln * 2 + 1] = a1;
    } else {
        const __half* add = (const __half*)addin;
        __half* out = (__half*)outv;
        float4 raw = ((const float4*)(add + (size_t)node * 32))[ln];
        const __half2* hp = (const __half2*)&raw;
        float2 a0 = __half22float2(hp[0]);
        float2 a1 = __half22float2(hp[1]);
        float2 a2 = __half22float2(hp[2]);
        float2 a3 = __half22float2(hp[3]);
        __half2 tmp[4];
        tmp[0] = __floats2half2_rn(acc[0] + a0.x, acc[1] + a0.y);
        tmp[1] = __floats2half2_rn(acc[2] + a1.x, acc[3] + a1.y);
        tmp[2] = __floats2half2_rn(acc[4] + a2.x, acc[5] + a2.y);
        tmp[3] = __floats2half2_rn(acc[6] + a3.x, acc[7] + a3.y);
        ((float4*)(out + (size_t)node * 32))[ln] = *(float4*)tmp;
    }
}

// ---------- FUSED both-layer MFMA GEMM ----------
__global__ __launch_bounds__(256) void gemm_fused(const __half* __restrict__ A0,
                                                  const __half* __restrict__ A1,
                                                  const __half* __restrict__ A2,
                                                  const __half* __restrict__ W1f,
                                                  const float* __restrict__ b1,
                                                  const __half* __restrict__ W2f,
                                                  const float* __restrict__ b2,
                                                  float* __restrict__ P0,
                                                  __half* __restrict__ G1,
                                                  __half* __restrict__ G2, int nnodes) {
    __shared__ __align__(16) __half htile[4][16 * 72];   // 9 KB
    const int wave = threadIdx.x >> 6;
    const int lane = threadIdx.x & 63;
    const int node0 = blockIdx.x * 64 + wave * 16;
    const int m = lane & 15;
    const int quad = lane >> 4;
    int arow = node0 + m;
    if (arow >= nnodes) arow = nnodes - 1;   // clamp: garbage rows never stored globally

    // ---- layer 1 ----
    const __half* Ap[3] = {A0, A1, A2};
    f16x8 a[6];
#pragma unroll
    for (int kh = 0; kh < 6; ++kh) {
        const __half* A = Ap[kh >> 1];
        a[kh] = *(const f16x8*)(A + (size_t)arow * 64 + ((kh & 1) << 5) + (quad << 3));
    }
    __half* ht = htile[wave];
#pragma unroll
    for (int ct = 0; ct < 4; ++ct) {
        f32x4 acc = {0.f, 0.f, 0.f, 0.f};
#pragma unroll
        for (int kh = 0; kh < 6; ++kh) {
            f16x8 b = *(const f16x8*)(W1f + ((size_t)(ct * 6 + kh) * 64 + lane) * 8);
            acc = __builtin_amdgcn_mfma_f32_16x16x32_f16(a[kh], b, acc, 0, 0, 0);
        }
        int col = (ct << 4) | m;
        float bias = b1[col];
#pragma unroll
        for (int r = 0; r < 4; ++r) {
            ht[(quad * 4 + r) * 72 + col] = __float2half(fmaxf(acc[r] + bias, 0.f));
        }
    }
    __syncthreads();

    // ---- layer 2: A-frags straight from the LDS tile ----
    f16x8 h0 = *(const f16x8*)(ht + m * 72 + (quad << 3));
    f16x8 h1 = *(const f16x8*)(ht + m * 72 + 32 + (quad << 3));
#pragma unroll
    for (int ct = 0; ct < 6; ++ct) {
        f32x4 acc = {0.f, 0.f, 0.f, 0.f};
        f16x8 b0 = *(const f16x8*)(W2f + ((size_t)(ct * 2 + 0) * 64 + lane) * 8);
        f16x8 b1v = *(const f16x8*)(W2f + ((size_t)(ct * 2 + 1) * 64 + lane) * 8);
        acc = __builtin_amdgcn_mfma_f32_16x16x32_f16(h0, b0, acc, 0, 0, 0);
        acc = __builtin_amdgcn_mfma_f32_16x16x32_f16(h1, b1v, acc, 0, 0, 0);
        int seg = ct >> 1;                      // wave-uniform
        int c = ((ct & 1) << 4) | m;            // col within segment
#pragma unroll
        for (int r = 0; r < 4; ++r) {
            int n = node0 + (quad << 2) + r;
            if (n >= nnodes) continue;
            float v = acc[r];
            if (seg == 0)      P0[(size_t)n * 32 + c] = v + b2[c];
            else if (seg == 1) G1[(size_t)n * 32 + c] = __float2half(v);
            else               G2[(size_t)n * 32 + c] = __float2half(v);
        }
    }
}

extern "C" void kernel_launch(void* const* d_in, const int* in_sizes, int n_in,
                              void* d_out, int out_size, void* d_ws, size_t ws_size,
                              hipStream_t stream) {
    const float* x  = (const float*)d_in[0];
    const int*   ei = (const int*)d_in[1];
    const float* W1 = (const float*)d_in[2];
    const float* b1 = (const float*)d_in[3];
    const float* W2 = (const float*)d_in[4];
    const float* b2 = (const float*)d_in[5];
    float* out = (float*)d_out;

    const int NN = N_NODES_C;
    const int NE = N_EDGES_C;
    const size_t HFEAT_BYTES = (size_t)NN * 64 * sizeof(__half);
    const size_t H32_BYTES = (size_t)NN * 32 * sizeof(__half);

    char* ws = (char*)d_ws;
    size_t off = 0;
    auto alloc = [&](size_t bytes) -> void* {
        void* p = ws + off;
        off += (bytes + 255) & ~(size_t)255;
        return p;
    };
    int*    bucket_cnt  = (int*)alloc((size_t)NBUK * 4);
    int*    bucket_base = (int*)alloc((size_t)(NBUK + 1) * 4);
    int*    bucket_next = (int*)alloc((size_t)NBUK * 4);
    int*    rowptr      = (int*)alloc((size_t)(NN + 1) * 4);
    float*  dis         = (float*)alloc((size_t)NN * 4);
    int*    staged      = (int*)alloc((size_t)NE * 4);
    int2*   colw        = (int2*)alloc((size_t)NE * 8);
    __half* xh          = (__half*)alloc(HFEAT_BYTES);
    __half* T1h         = (__half*)alloc(HFEAT_BYTES);   // layer1: T1; layer2: G1
    __half* T2h         = (__half*)alloc(HFEAT_BYTES);   // layer1: T2; layer2: G2
    __half* Qh          = (__half*)alloc(H32_BYTES);
    float*  P0          = (float*)alloc((size_t)NN * 32 * 4);
    __half* W1f         = (__half*)alloc((size_t)4 * 6 * 64 * 8 * 2);   // 24 KB
    __half* W2f         = (__half*)alloc((size_t)6 * 2 * 64 * 8 * 2);   // 12 KB

    const int PROPB = (NN + 31) / 32;     // prop64: 32 nodes/block
    const int PROP32B = (NN + 63) / 64;   // prop32: 64 nodes/block
    const int CONV4 = NN * 64 / 4;
    const int CONVB = (CONV4 + 255) / 256;
    const int BINB = (NE + CHUNK - 1) / CHUNK;
    const int GEMMB = (NN + 63) / 64;
    const int FOLDB = 1 + (18432 + 255) / 256;

    // ---- CSR build (bucket-atomic) + weight packing + x->fp16 ----
    hipMemsetAsync(bucket_cnt, 0, (size_t)NBUK * 4, stream);
    hist_f2h<<<BINB + CONVB, 256, 0, stream>>>(ei, bucket_cnt, x, xh, NE, CONV4, BINB);
    scan_fold<<<FOLDB, 256, 0, stream>>>(bucket_cnt, bucket_base, bucket_next, NBUK,
                                         W1, W2, W1f, W2f);
    bin_stage<<<BINB, 256, 0, stream>>>(ei, bucket_next, staged, NE);
    bin_count<<<NBUK, 256, 0, stream>>>(staged, bucket_base, rowptr, dis, NN, NE);
    bin_place<<<NBUK, 256, 0, stream>>>(staged, rowptr, dis, colw, NN);

    // ---- layer 1 props, then fused both-layer GEMM ----
    prop_gather_h<<<PROPB, 256, 0, stream>>>(xh, rowptr, colw, T1h, NN);
    prop_gather_h<<<PROPB, 256, 0, stream>>>(T1h, rowptr, colw, T2h, NN);
    gemm_fused<<<GEMMB, 256, 0, stream>>>(xh, T1h, T2h, W1f, b1, W2f, b2, P0, T1h, T2h, NN);

    // ---- layer 2 (factored): out = P0 + prop(G1 + prop(G2)) ----
    prop_gather32<false><<<PROP32B, 256, 0, stream>>>(T2h, rowptr, colw, T1h, Qh, NN);
    prop_gather32<true><<<PROP32B, 256, 0, stream>>>(Qh, rowptr, colw, P0, out, NN);
}